// Round 4
// baseline (6031.109 us; speedup 1.0000x reference)
//
#include <hip/hip_runtime.h>
#include <math.h>

// TopK router: logits = x @ W^T + b ; top-2 over E=64 ; sparse softmax.
// x: [T=16384, D=2048] f32, W: [64, 2048] f32, b: [64] f32.
// d_out: [T*64] router probs f32, then [T*2] top-k indices as f32.
//
// R4: R3's DMA-pipeline idea, de-spilled. R3 spilled dacc to scratch
// (WRITE_SIZE 432 MB) because the accumulators were captured by reference
// in a lambda (address-taken) inside asm "memory" fences. Now: flat macro
// body, plain unrolled arrays (SROA -> registers), 4-buffer LDS ring,
// 3-chunk-deep prefetch with counted vmcnt(6) (never 0 in the main loop),
// no in-loop s_barrier (buffers are wave-private). x flows HBM->LDS via
// global_load_lds (vector path, deep MLP); compute reads x as broadcast
// ds_read_b128; W is per-lane loads (512 KB, L2-resident).

#define RD 2048
#define RE 64
#define CHUNK 128                 // floats per token per chunk
#define NCHUNK (RD / CHUNK)       // 16
#define NBUF 4
#define NWAVES 4
#define TPW 4                     // tokens per wave
#define TPB (NWAVES * TPW)        // 16 tokens per block

__device__ __forceinline__ void stage16(const float* g, float* l) {
    __builtin_amdgcn_global_load_lds(
        (const __attribute__((address_space(1))) void*)g,
        (__attribute__((address_space(3))) void*)l,
        16 /*bytes per lane*/, 0 /*offset*/, 0 /*aux*/);
}

// stage chunk C (two DMA instrs: tokens 0-1, tokens 2-3 of this wave)
#define STAGE(C) do {                                                  \
    stage16(gsrc0 + (size_t)(C) * CHUNK, &xs[(C) & 3][wv][0][0]);      \
    stage16(gsrc1 + (size_t)(C) * CHUNK, &xs[(C) & 3][wv][2][0]);      \
} while (0)

// compute chunk C out of buffer (C&3); fp32 fma chains of 8 per float4
// slot (32-float s-blocks), f64 accumulate per s-block.
#define COMPUTE(C) do {                                                \
    const float* wc_ = wrow + (size_t)(C) * CHUNK;                     \
    _Pragma("unroll")                                                  \
    for (int s_ = 0; s_ < 4; ++s_) {                                   \
        const float4* wp_ = (const float4*)(wc_ + s_ * 32);            \
        const float4 w0_ = wp_[0], w1_ = wp_[1], w2_ = wp_[2], w3_ = wp_[3]; \
        const float4 w4_ = wp_[4], w5_ = wp_[5], w6_ = wp_[6], w7_ = wp_[7]; \
        _Pragma("unroll")                                              \
        for (int tt_ = 0; tt_ < TPW; ++tt_) {                          \
            const float4* xp_ = (const float4*)&xs[(C) & 3][wv][tt_][s_ * 32]; \
            float4 a_;                                                 \
            a_.x = xp_[0].x * w0_.x; a_.y = xp_[0].y * w0_.y;          \
            a_.z = xp_[0].z * w0_.z; a_.w = xp_[0].w * w0_.w;          \
            a_.x = fmaf(xp_[1].x, w1_.x, a_.x); a_.y = fmaf(xp_[1].y, w1_.y, a_.y); \
            a_.z = fmaf(xp_[1].z, w1_.z, a_.z); a_.w = fmaf(xp_[1].w, w1_.w, a_.w); \
            a_.x = fmaf(xp_[2].x, w2_.x, a_.x); a_.y = fmaf(xp_[2].y, w2_.y, a_.y); \
            a_.z = fmaf(xp_[2].z, w2_.z, a_.z); a_.w = fmaf(xp_[2].w, w2_.w, a_.w); \
            a_.x = fmaf(xp_[3].x, w3_.x, a_.x); a_.y = fmaf(xp_[3].y, w3_.y, a_.y); \
            a_.z = fmaf(xp_[3].z, w3_.z, a_.z); a_.w = fmaf(xp_[3].w, w3_.w, a_.w); \
            a_.x = fmaf(xp_[4].x, w4_.x, a_.x); a_.y = fmaf(xp_[4].y, w4_.y, a_.y); \
            a_.z = fmaf(xp_[4].z, w4_.z, a_.z); a_.w = fmaf(xp_[4].w, w4_.w, a_.w); \
            a_.x = fmaf(xp_[5].x, w5_.x, a_.x); a_.y = fmaf(xp_[5].y, w5_.y, a_.y); \
            a_.z = fmaf(xp_[5].z, w5_.z, a_.z); a_.w = fmaf(xp_[5].w, w5_.w, a_.w); \
            a_.x = fmaf(xp_[6].x, w6_.x, a_.x); a_.y = fmaf(xp_[6].y, w6_.y, a_.y); \
            a_.z = fmaf(xp_[6].z, w6_.z, a_.z); a_.w = fmaf(xp_[6].w, w6_.w, a_.w); \
            a_.x = fmaf(xp_[7].x, w7_.x, a_.x); a_.y = fmaf(xp_[7].y, w7_.y, a_.y); \
            a_.z = fmaf(xp_[7].z, w7_.z, a_.z); a_.w = fmaf(xp_[7].w, w7_.w, a_.w); \
            dacc[tt_] += (double)((a_.x + a_.y) + (a_.z + a_.w));      \
        }                                                              \
    }                                                                  \
} while (0)

#define WAITV(N) do {                                                  \
    asm volatile("s_waitcnt vmcnt(" #N ")" ::: "memory");              \
    __builtin_amdgcn_sched_barrier(0);                                 \
} while (0)

__global__ __launch_bounds__(256, 4) void topk_router_kernel(
    const float* __restrict__ x,
    const float* __restrict__ W,
    const float* __restrict__ b,
    float* __restrict__ out_router,
    float* __restrict__ out_idx,
    int total_tokens)
{
    const int lane = threadIdx.x & 63;
    const int wv = __builtin_amdgcn_readfirstlane((int)(threadIdx.x >> 6));
    const int tok0 = blockIdx.x * TPB + wv * TPW;

    // xs[buf][wave][token][128 floats]; 32 KB, wave-private slices
    __shared__ __align__(16) float xs[NBUF][NWAVES][TPW][CHUNK];

    // DMA instr i covers tokens tok0 + 2i + (lane>>5); lane&31 is the 16B
    // slice within the 512B token-chunk (DMA dest = LDS base + lane*16).
    const int tmax = total_tokens - 1;
    const int r0 = min(tok0 + 0 + (lane >> 5), tmax);
    const int r1 = min(tok0 + 2 + (lane >> 5), tmax);
    const float* gsrc0 = x + (size_t)r0 * RD + (lane & 31) * 4;
    const float* gsrc1 = x + (size_t)r1 * RD + (lane & 31) * 4;
    const float* wrow  = W + (size_t)lane * RD;

    double dacc[TPW] = {0.0, 0.0, 0.0, 0.0};

    // prologue: 3 chunks in flight
    STAGE(0);
    STAGE(1);
    STAGE(2);

#pragma unroll
    for (int c = 0; c < NCHUNK - 3; ++c) {
        __builtin_amdgcn_sched_barrier(0);
        STAGE(c + 3);
        WAITV(6);      // chunks <= c complete; c+1..c+3 stay in flight
        COMPUTE(c);
    }
    WAITV(4);
    COMPUTE(NCHUNK - 3);
    WAITV(2);
    COMPUTE(NCHUNK - 2);
    WAITV(0);
    COMPUTE(NCHUNK - 1);

    // ---- epilogue: top-2 + sparse softmax (wave-private tokens)
    const double bias = (double)b[lane];

#pragma unroll
    for (int tt = 0; tt < TPW; ++tt) {
        const int token = tok0 + tt;
        if (token >= total_tokens) break;
        const double v = dacc[tt] + bias;

        // argmax #1 (value desc, tie -> lower lane)
        double bestv = v;
        int besti = lane;
#pragma unroll
        for (int off = 32; off > 0; off >>= 1) {
            double ov = __shfl_xor(bestv, off, 64);
            int oi = __shfl_xor(besti, off, 64);
            if (ov > bestv || (ov == bestv && oi < besti)) { bestv = ov; besti = oi; }
        }

        // argmax #2 excluding winner
        double v2 = (lane == besti) ? -INFINITY : v;
        double best2v = v2;
        int best2i = lane;
#pragma unroll
        for (int off = 32; off > 0; off >>= 1) {
            double ov = __shfl_xor(best2v, off, 64);
            int oi = __shfl_xor(best2i, off, 64);
            if (ov > best2v || (ov == best2v && oi < best2i)) { best2v = ov; best2i = oi; }
        }

        // 2-element softmax; all other experts exactly 0
        const float e2 = expf((float)(best2v - bestv));
        const float denom = 1.0f + e2;
        const float p1 = 1.0f / denom;
        const float p2 = e2 / denom;

        float outv = 0.0f;
        if (lane == besti) outv = p1;
        else if (lane == best2i) outv = p2;
        out_router[(size_t)token * RE + lane] = outv;

        if (lane == 0) {
            out_idx[(size_t)token * 2 + 0] = (float)besti;
            out_idx[(size_t)token * 2 + 1] = (float)best2i;
        }
    }
}

extern "C" void kernel_launch(void* const* d_in, const int* in_sizes, int n_in,
                              void* d_out, int out_size, void* d_ws, size_t ws_size,
                              hipStream_t stream) {
    const float* x = (const float*)d_in[0];
    const float* W = (const float*)d_in[1];
    const float* b = (const float*)d_in[2];

    const int E = in_sizes[2];                 // 64
    const int D = in_sizes[1] / E;             // 2048
    const int T = in_sizes[0] / D;             // 16384
    (void)E; (void)D;

    float* out_router = (float*)d_out;
    float* out_idx = out_router + (size_t)T * RE;

    const int grid = (T + TPB - 1) / TPB;      // 1024

    topk_router_kernel<<<grid, 256, 0, stream>>>(x, W, b, out_router, out_idx, T);
}

// Round 5
// 101.906 us; speedup vs baseline: 59.1832x; 59.1832x over previous
//
#include <hip/hip_runtime.h>
#include <math.h>

// TopK router: logits = x @ W^T + b ; top-2 over E=64 ; sparse softmax.
// x: [T=16384, D=2048] f32, W: [64, 2048] f32, b: [64] f32.
// d_out: [T*64] router probs f32, then [T*2] top-k indices as f32.
//
// R5: back to R2's proven structure (block = 16 tokens, 4 waves, each wave
// owns a K-quarter, lane = expert), with the one diagnosed fix: x moves off
// the scalar-load path (R2: s_load streams -> 33% VALUBusy) onto the vector
// path via plain reg->LDS staging, issue-early/write-late (T14), double
// buffer, #pragma unroll 1 (one chunk of stage regs live -> no spill).
// Compute reads x as broadcast ds_read_b128 (uniform addr, conflict-free);
// W stays per-lane vector loads (512 KB, L2-resident). No inline asm, no
// DMA intrinsics, no lambdas (R3/R4 post-mortems: both spilled to scratch).
// f64 accumulate per 32-float block, summation order identical to R2
// (indices verified exact there).

#define RD 2048
#define RE 64
#define NW 4                    // waves per block
#define TPB 16                  // tokens per block
#define DQ (RD / NW)            // 512 k-floats per wave
#define CK 64                   // chunk: k-floats staged per iteration
#define NC (DQ / CK)            // 8 chunks
#define ROWP 68                 // padded LDS row (floats) -> balanced banks

struct X4 { float4 a, b, c, d; };

__device__ __forceinline__ X4 ldx(const float* p) {
    X4 r;
    r.a = *(const float4*)(p + 0);
    r.b = *(const float4*)(p + 16);
    r.c = *(const float4*)(p + 32);
    r.d = *(const float4*)(p + 48);
    return r;
}
__device__ __forceinline__ void stx(float* p, const X4 r) {
    *(float4*)(p + 0)  = r.a;
    *(float4*)(p + 16) = r.b;
    *(float4*)(p + 32) = r.c;
    *(float4*)(p + 48) = r.d;
}

// One chunk of FMA work: chunk index C (0..NC-1), reads LDS buffer (C&1).
// 2 s-blocks of 32 floats; fp32 fma chains of 8 float4s; f64 accumulate.
// Summation order identical to R2.
#define COMPUTE_BODY(C) do {                                               \
    const float* xb_ = &xs[wq][(C) & 1][0][0];                             \
    const float* wc_ = wrow + (C) * CK;                                    \
    _Pragma("unroll")                                                      \
    for (int s_ = 0; s_ < 2; ++s_) {                                       \
        const float4* wp_ = (const float4*)(wc_ + s_ * 32);                \
        const float4 w0_ = wp_[0], w1_ = wp_[1], w2_ = wp_[2], w3_ = wp_[3]; \
        const float4 w4_ = wp_[4], w5_ = wp_[5], w6_ = wp_[6], w7_ = wp_[7]; \
        _Pragma("unroll")                                                  \
        for (int tt_ = 0; tt_ < TPB; ++tt_) {                              \
            const float4* xp_ = (const float4*)(xb_ + tt_ * ROWP + s_ * 32); \
            float4 a_;                                                     \
            a_.x = xp_[0].x * w0_.x; a_.y = xp_[0].y * w0_.y;              \
            a_.z = xp_[0].z * w0_.z; a_.w = xp_[0].w * w0_.w;              \
            a_.x = fmaf(xp_[1].x, w1_.x, a_.x); a_.y = fmaf(xp_[1].y, w1_.y, a_.y); \
            a_.z = fmaf(xp_[1].z, w1_.z, a_.z); a_.w = fmaf(xp_[1].w, w1_.w, a_.w); \
            a_.x = fmaf(xp_[2].x, w2_.x, a_.x); a_.y = fmaf(xp_[2].y, w2_.y, a_.y); \
            a_.z = fmaf(xp_[2].z, w2_.z, a_.z); a_.w = fmaf(xp_[2].w, w2_.w, a_.w); \
            a_.x = fmaf(xp_[3].x, w3_.x, a_.x); a_.y = fmaf(xp_[3].y, w3_.y, a_.y); \
            a_.z = fmaf(xp_[3].z, w3_.z, a_.z); a_.w = fmaf(xp_[3].w, w3_.w, a_.w); \
            a_.x = fmaf(xp_[4].x, w4_.x, a_.x); a_.y = fmaf(xp_[4].y, w4_.y, a_.y); \
            a_.z = fmaf(xp_[4].z, w4_.z, a_.z); a_.w = fmaf(xp_[4].w, w4_.w, a_.w); \
            a_.x = fmaf(xp_[5].x, w5_.x, a_.x); a_.y = fmaf(xp_[5].y, w5_.y, a_.y); \
            a_.z = fmaf(xp_[5].z, w5_.z, a_.z); a_.w = fmaf(xp_[5].w, w5_.w, a_.w); \
            a_.x = fmaf(xp_[6].x, w6_.x, a_.x); a_.y = fmaf(xp_[6].y, w6_.y, a_.y); \
            a_.z = fmaf(xp_[6].z, w6_.z, a_.z); a_.w = fmaf(xp_[6].w, w6_.w, a_.w); \
            a_.x = fmaf(xp_[7].x, w7_.x, a_.x); a_.y = fmaf(xp_[7].y, w7_.y, a_.y); \
            a_.z = fmaf(xp_[7].z, w7_.z, a_.z); a_.w = fmaf(xp_[7].w, w7_.w, a_.w); \
            dacc[tt_] += (double)((a_.x + a_.y) + (a_.z + a_.w));          \
        }                                                                  \
    }                                                                      \
} while (0)

__global__ __launch_bounds__(256, 4) void topk_router_kernel(
    const float* __restrict__ x,
    const float* __restrict__ W,
    const float* __restrict__ b,
    float* __restrict__ out_router,
    float* __restrict__ out_idx,
    int total_tokens)
{
    const int lane = threadIdx.x & 63;
    const int wq = __builtin_amdgcn_readfirstlane((int)(threadIdx.x >> 6)); // K-quarter
    const int tok0 = blockIdx.x * TPB;

    // xs[wave][buf][token][ROWP]: 4*2*16*68*4 = 34816 B -> 4 blocks/CU.
    // Each wave touches only xs[wq] -> no cross-wave hazard, no barriers
    // in the main loop. The f64 partial buffer aliases this region later.
    __shared__ __align__(16) float xs[NW][2][TPB][ROWP];

    // Staging: 4 lanes per token row; lane covers 4 float4s at stride 64B.
    const int tmax = total_tokens - 1;
    const int stok = min(tok0 + (lane >> 2), tmax);
    const float* gsrc = x + (size_t)stok * RD + wq * DQ + (lane & 3) * 4;
    float* ldst = &xs[wq][0][lane >> 2][(lane & 3) * 4];
    const float* wrow = W + (size_t)lane * RD + wq * DQ;

    double dacc[TPB];
#pragma unroll
    for (int t = 0; t < TPB; ++t) dacc[t] = 0.0;

    // prologue: chunk 0 -> buf 0
    {
        X4 c0 = ldx(gsrc);
        stx(ldst, c0);
    }

    // main loop: issue chunk c+1 loads early, compute chunk c, write c+1 late
#pragma unroll 1
    for (int c = 0; c < NC - 1; ++c) {
        X4 nxt = ldx(gsrc + (c + 1) * CK);
        COMPUTE_BODY(c);
        stx(ldst + ((c + 1) & 1) * (TPB * ROWP), nxt);
    }
    COMPUTE_BODY(NC - 1);

    // ---- combine K-quarters via f64 partials aliased into this wave's xs slice
    double* pd_own = (double*)&xs[wq][0][0][0];   // 16 tok * 64 lanes * 8B = 8192 B
#pragma unroll
    for (int t = 0; t < TPB; ++t) pd_own[t * RE + lane] = dacc[t];
    __syncthreads();

    const double bias = (double)b[lane];

    // epilogue: wave wq owns tokens [wq*4, wq*4+4)
#pragma unroll
    for (int tt = 0; tt < TPB / NW; ++tt) {
        const int t = wq * (TPB / NW) + tt;
        const int token = tok0 + t;
        if (token >= total_tokens) break;

        const double* p0 = (const double*)&xs[0][0][0][0];
        const double* p1 = (const double*)&xs[1][0][0][0];
        const double* p2 = (const double*)&xs[2][0][0][0];
        const double* p3 = (const double*)&xs[3][0][0][0];
        const double v = p0[t * RE + lane] + p1[t * RE + lane]
                       + p2[t * RE + lane] + p3[t * RE + lane] + bias;

        // argmax #1 (value desc, tie -> lower lane)
        double bestv = v;
        int besti = lane;
#pragma unroll
        for (int off = 32; off > 0; off >>= 1) {
            double ov = __shfl_xor(bestv, off, 64);
            int oi = __shfl_xor(besti, off, 64);
            if (ov > bestv || (ov == bestv && oi < besti)) { bestv = ov; besti = oi; }
        }

        // argmax #2 excluding winner
        double v2 = (lane == besti) ? -INFINITY : v;
        double best2v = v2;
        int best2i = lane;
#pragma unroll
        for (int off = 32; off > 0; off >>= 1) {
            double ov = __shfl_xor(best2v, off, 64);
            int oi = __shfl_xor(best2i, off, 64);
            if (ov > best2v || (ov == best2v && oi < best2i)) { best2v = ov; best2i = oi; }
        }

        // 2-element softmax; all other experts exactly 0
        const float e2 = expf((float)(best2v - bestv));
        const float denom = 1.0f + e2;
        const float p1v = 1.0f / denom;
        const float p2v = e2 / denom;

        float outv = 0.0f;
        if (lane == besti) outv = p1v;
        else if (lane == best2i) outv = p2v;
        out_router[(size_t)token * RE + lane] = outv;

        if (lane == 0) {
            out_idx[(size_t)token * 2 + 0] = (float)besti;
            out_idx[(size_t)token * 2 + 1] = (float)best2i;
        }
    }
}

extern "C" void kernel_launch(void* const* d_in, const int* in_sizes, int n_in,
                              void* d_out, int out_size, void* d_ws, size_t ws_size,
                              hipStream_t stream) {
    const float* x = (const float*)d_in[0];
    const float* W = (const float*)d_in[1];
    const float* b = (const float*)d_in[2];

    const int E = in_sizes[2];                 // 64
    const int D = in_sizes[1] / E;             // 2048
    const int T = in_sizes[0] / D;             // 16384
    (void)E; (void)D;

    float* out_router = (float*)d_out;
    float* out_idx = out_router + (size_t)T * RE;

    const int grid = (T + TPB - 1) / TPB;      // 1024

    topk_router_kernel<<<grid, 256, 0, stream>>>(x, W, b, out_router, out_idx, T);
}